// Round 15
// baseline (1725.779 us; speedup 1.0000x reference)
//
#include <hip/hip_runtime.h>
#include <math.h>

#define BB 2
#define LL 2048
#define DM 1024
#define NH 16
#define HD 64

__device__ __forceinline__ unsigned mono32(float f) {
    unsigned u = __float_as_uint(f);
    return (u & 0x80000000u) ? ~u : (u | 0x80000000u);
}
__device__ __forceinline__ float unmono32(unsigned m) {
    const unsigned u = (m & 0x80000000u) ? (m & 0x7FFFFFFFu) : ~m;
    return __uint_as_float(u);
}

// ---------------------------------------------------------------------------
// 1024x1024 transpose: out[k][n] = in[n][k]
// ---------------------------------------------------------------------------
__global__ __launch_bounds__(256) void transpose1024(
    const float* __restrict__ in, float* __restrict__ out)
{
    __shared__ float t[32][33];
    const int bx = blockIdx.x * 32, by = blockIdx.y * 32;
    const int tx = threadIdx.x & 31, ty = threadIdx.x >> 5;
    for (int r = ty; r < 32; r += 8)
        t[r][tx] = in[(size_t)(by + r) * DM + bx + tx];
    __syncthreads();
    for (int r = ty; r < 32; r += 8)
        out[(size_t)(bx + r) * DM + by + tx] = t[tx][r];
}

// ---------------------------------------------------------------------------
// Bit-emulated f32 projection (numpy -> OpenBLAS sgemm, Zen/Haswell):
// K-panels (384,320,320); serial ascending-k FMA chain per panel; C += panel;
// then +bias. Scatter to [B,H,L,D]. Wt is W transposed [k][n].
// v2: 4 columns/thread (float4 W loads) + float4 LDS x reads; per-output
// fmaf chain IDENTICAL (k ascending per (m,n), panel C+= order kept).
// DO NOT TOUCH chain order: Q/K bit-exactness determines top-k selection.
// ---------------------------------------------------------------------------
__global__ __launch_bounds__(256) void proj_emul(
    const float* __restrict__ x, const float* __restrict__ Wt,
    const float* __restrict__ bias, float* __restrict__ outp)
{
    __shared__ float xs[8][DM];   // 32 KB
    const int tid = threadIdx.x;
    const int n4  = tid * 4;                 // 4 consecutive cols per thread
    const int m0  = blockIdx.x * 8;

    for (int i = tid; i < 8 * 256; i += 256) {
        const int r = i >> 8, c4 = (i & 255) << 2;
        *(float4*)&xs[r][c4] = *(const float4*)&x[(size_t)(m0 + r) * DM + c4];
    }
    __syncthreads();

    const int kbound[4] = {0, 384, 704, 1024};   // OpenBLAS Zen panel splits

    float S[8][4] = {};
#pragma unroll
    for (int p = 0; p < 3; p++) {
        float P[8][4] = {};
        for (int k = kbound[p]; k < kbound[p + 1]; k += 4) {
            const float4 w0 = *(const float4*)&Wt[(size_t)(k + 0) * DM + n4];
            const float4 w1 = *(const float4*)&Wt[(size_t)(k + 1) * DM + n4];
            const float4 w2 = *(const float4*)&Wt[(size_t)(k + 2) * DM + n4];
            const float4 w3 = *(const float4*)&Wt[(size_t)(k + 3) * DM + n4];
#pragma unroll
            for (int m = 0; m < 8; m++) {
                const float4 xv = *(const float4*)&xs[m][k];
                P[m][0] = fmaf(xv.x, w0.x, P[m][0]);
                P[m][1] = fmaf(xv.x, w0.y, P[m][1]);
                P[m][2] = fmaf(xv.x, w0.z, P[m][2]);
                P[m][3] = fmaf(xv.x, w0.w, P[m][3]);
                P[m][0] = fmaf(xv.y, w1.x, P[m][0]);
                P[m][1] = fmaf(xv.y, w1.y, P[m][1]);
                P[m][2] = fmaf(xv.y, w1.z, P[m][2]);
                P[m][3] = fmaf(xv.y, w1.w, P[m][3]);
                P[m][0] = fmaf(xv.z, w2.x, P[m][0]);
                P[m][1] = fmaf(xv.z, w2.y, P[m][1]);
                P[m][2] = fmaf(xv.z, w2.z, P[m][2]);
                P[m][3] = fmaf(xv.z, w2.w, P[m][3]);
                P[m][0] = fmaf(xv.w, w3.x, P[m][0]);
                P[m][1] = fmaf(xv.w, w3.y, P[m][1]);
                P[m][2] = fmaf(xv.w, w3.z, P[m][2]);
                P[m][3] = fmaf(xv.w, w3.w, P[m][3]);
            }
        }
#pragma unroll
        for (int m = 0; m < 8; m++) {
#pragma unroll
            for (int j = 0; j < 4; j++) S[m][j] += P[m][j];  // C += panel
        }
    }

    const float4 b4v = *(const float4*)&bias[n4];
    const int h = n4 / HD, d0 = n4 % HD;   // 4 cols stay in one head
#pragma unroll
    for (int m = 0; m < 8; m++) {
        const int mm = m0 + m;
        const int b = mm / LL, l = mm % LL;
        float4 o;
        o.x = S[m][0] + b4v.x; o.y = S[m][1] + b4v.y;
        o.z = S[m][2] + b4v.z; o.w = S[m][3] + b4v.w;
        *(float4*)&outp[(((size_t)b * NH + h) * LL + l) * HD + d0] = o;
    }
}

// ---------------------------------------------------------------------------
// f32 GEMM for V (MODE 0 scatter) and output projection (MODE 1).
// ---------------------------------------------------------------------------
template <int MODE>
__global__ __launch_bounds__(256) void gemm_f32(
    const float* __restrict__ A, const float* __restrict__ W,
    const float* __restrict__ bias, float* __restrict__ out,
    int M, int N, int K)
{
    __shared__ float As[16][64];
    __shared__ float Bs[16][64];
    const int tid = threadIdx.x;
    const int m0 = blockIdx.y * 64;
    const int n0 = blockIdx.x * 64;
    const int tx = tid & 15, ty = tid >> 4;
    const int lr = tid >> 2, lc = (tid & 3) * 4;

    float acc[4][4] = {};

    for (int k0 = 0; k0 < K; k0 += 16) {
        float4 a4 = *(const float4*)&A[(size_t)(m0 + lr) * K + k0 + lc];
        float4 b4 = *(const float4*)&W[(size_t)(n0 + lr) * K + k0 + lc];
        __syncthreads();
        As[lc + 0][lr] = a4.x; As[lc + 1][lr] = a4.y;
        As[lc + 2][lr] = a4.z; As[lc + 3][lr] = a4.w;
        Bs[lc + 0][lr] = b4.x; Bs[lc + 1][lr] = b4.y;
        Bs[lc + 2][lr] = b4.z; Bs[lc + 3][lr] = b4.w;
        __syncthreads();
#pragma unroll
        for (int kk = 0; kk < 16; kk++) {
            float4 av = *(const float4*)&As[kk][ty * 4];
            float4 bv = *(const float4*)&Bs[kk][tx * 4];
            float a[4] = {av.x, av.y, av.z, av.w};
            float b[4] = {bv.x, bv.y, bv.z, bv.w};
#pragma unroll
            for (int i = 0; i < 4; i++)
#pragma unroll
                for (int j = 0; j < 4; j++)
                    acc[i][j] = fmaf(a[i], b[j], acc[i][j]);
        }
    }

#pragma unroll
    for (int i = 0; i < 4; i++) {
        const int m = m0 + ty * 4 + i;
#pragma unroll
        for (int j = 0; j < 4; j++) {
            const int n = n0 + tx * 4 + j;
            const float v = acc[i][j] + bias[n];
            if (MODE == 0) {
                const int b = m / LL, l = m % LL;
                const int h = n / HD, d = n % HD;
                out[(((size_t)b * NH + h) * LL + l) * HD + d] = v;
            } else {
                out[(size_t)m * N + n] = v;
            }
        }
    }
}

// ---------------------------------------------------------------------------
// Attention: score_np (producer) + select_np (consumer); split (R7) killed
// the structural 64-reg live range that spilled in v3-v6.
//
// score_np v6 (R13/R14/R15): q via WAVE-UNIFORM GLOBAL reads (readfirstlane
//   -> SGPR base -> scalar-load path), qsh LDS deleted.
//   R12's v2 was LDS-pipe bound: 80 ds_read_b128/tile/wave, of which 64
//   were q reads whose value is IDENTICAL across lanes. Uniform loads
//   don't need the LDS pipe: LDS reads/tile drop 80 -> 16 (k only),
//   LDS ~512 cy < VALU ~1024 cy -> VALU-bound. LDS 38912 -> 34816 B
//   -> 4 blocks/CU (occupancy 2x). Per-lane live state unchanged (~70
//   regs, below the ~80-100 VGPR spill wall probed in R9-R11).
//   Chain values and order IDENTICAL (t asc, sub desc, x/y/z/w,
//   ((x+y)+(z+w))*0.125, contract off) -> bit-exact.
// select_np: R0-proven consumer; mv[32] short live range -> registers.
// ---------------------------------------------------------------------------
__global__ __launch_bounds__(256) void score_np(
    const float* __restrict__ Qf, const float* __restrict__ Kf,
    unsigned* __restrict__ scw, int bh0)
{
#pragma clang fp contract(off)
    const int tid  = threadIdx.x;
    const int lane = tid & 63;
    const int wv   = tid >> 6;
    const int l0   = blockIdx.x * 16;
    const int bhl  = blockIdx.y;
    const int bh   = bh0 + bhl;

    __shared__ float kt[2][64][68];    // 34 KB K tiles (+4 pad per row)

    const float* __restrict__ Kb = Kf + (size_t)bh * LL * HD;

    // stage K tile 0 (64 rows x 16 float4; coalesced)
#pragma unroll
    for (int i = 0; i < 4; i++) {
        const int idx = i * 256 + tid;
        *(float4*)&kt[0][idx >> 4][(idx & 15) * 4] =
            *(const float4*)&Kb[(size_t)(idx >> 4) * HD + (idx & 15) * 4];
    }
    __syncthreads();

    const int r0 = wv * 4;
    // wave-uniform q row base -> SGPR (scalar-load path); element index
    // fits int (max 32*2048*64 = 4.2M)
    const int qoff = __builtin_amdgcn_readfirstlane(
        (bh * LL + l0 + r0) * HD);
    const float* __restrict__ q0 = Qf + qoff;
    const float* __restrict__ q1 = q0 + HD;
    const float* __restrict__ q2 = q1 + HD;
    const float* __restrict__ q3 = q2 + HD;

    unsigned* __restrict__ s0 = scw + ((size_t)bhl * LL + l0 + r0 + 0) * LL;
    unsigned* __restrict__ s1 = scw + ((size_t)bhl * LL + l0 + r0 + 1) * LL;
    unsigned* __restrict__ s2 = scw + ((size_t)bhl * LL + l0 + r0 + 2) * LL;
    unsigned* __restrict__ s3 = scw + ((size_t)bhl * LL + l0 + r0 + 3) * LL;

    for (int tile = 0; tile < 32; tile++) {
        const int buf = tile & 1;
        float4 pf0, pf1, pf2, pf3;
        if (tile < 31) {
            const float* src = Kb + (size_t)(tile + 1) * 64 * HD;
            pf0 = *(const float4*)&src[(size_t)((0 * 256 + tid) >> 4) * HD + ((0 * 256 + tid) & 15) * 4];
            pf1 = *(const float4*)&src[(size_t)((1 * 256 + tid) >> 4) * HD + ((1 * 256 + tid) & 15) * 4];
            pf2 = *(const float4*)&src[(size_t)((2 * 256 + tid) >> 4) * HD + ((2 * 256 + tid) & 15) * 4];
            pf3 = *(const float4*)&src[(size_t)((3 * 256 + tid) >> 4) * HD + ((3 * 256 + tid) & 15) * 4];
        }

        // scores for key = tile*64 + lane, rows r0..r0+3 (bit-exact chains;
        // q read via uniform global loads, same values/order as LDS path)
        float ax0 = 0, ay0 = 0, az0 = 0, aw0 = 0;
        float ax1 = 0, ay1 = 0, az1 = 0, aw1 = 0;
        float ax2 = 0, ay2 = 0, az2 = 0, aw2 = 0;
        float ax3 = 0, ay3 = 0, az3 = 0, aw3 = 0;
        const float* krow = &kt[buf][lane][0];
#pragma unroll
        for (int t = 0; t < 4; t++) {
#pragma unroll
            for (int sub = 3; sub >= 0; sub--) {
                const int d4 = 4 * t + sub;
                const float4 kf = *(const float4*)&krow[d4 * 4];
                const float4 qa = *(const float4*)&q0[d4 * 4];
                const float4 qb = *(const float4*)&q1[d4 * 4];
                const float4 qc = *(const float4*)&q2[d4 * 4];
                const float4 qd = *(const float4*)&q3[d4 * 4];
                ax0 = qa.x * kf.x + ax0; ay0 = qa.y * kf.y + ay0;
                az0 = qa.z * kf.z + az0; aw0 = qa.w * kf.w + aw0;
                ax1 = qb.x * kf.x + ax1; ay1 = qb.y * kf.y + ay1;
                az1 = qb.z * kf.z + az1; aw1 = qb.w * kf.w + aw1;
                ax2 = qc.x * kf.x + ax2; ay2 = qc.y * kf.y + ay2;
                az2 = qc.z * kf.z + az2; aw2 = qc.w * kf.w + aw2;
                ax3 = qd.x * kf.x + ax3; ay3 = qd.y * kf.y + ay3;
                az3 = qd.z * kf.z + az3; aw3 = qd.w * kf.w + aw3;
            }
        }
        // immediate coalesced stores (lane-consecutive u32), no live range
        s0[tile * 64 + lane] = mono32(((ax0 + ay0) + (az0 + aw0)) * 0.125f);
        s1[tile * 64 + lane] = mono32(((ax1 + ay1) + (az1 + aw1)) * 0.125f);
        s2[tile * 64 + lane] = mono32(((ax2 + ay2) + (az2 + aw2)) * 0.125f);
        s3[tile * 64 + lane] = mono32(((ax3 + ay3) + (az3 + aw3)) * 0.125f);

        if (tile < 31) {
            // single barrier per tile: reads kt[buf] / writes kt[buf^1]
            // are disjoint buffers.
            *(float4*)&kt[buf ^ 1][(0 * 256 + tid) >> 4][((0 * 256 + tid) & 15) * 4] = pf0;
            *(float4*)&kt[buf ^ 1][(1 * 256 + tid) >> 4][((1 * 256 + tid) & 15) * 4] = pf1;
            *(float4*)&kt[buf ^ 1][(2 * 256 + tid) >> 4][((2 * 256 + tid) & 15) * 4] = pf2;
            *(float4*)&kt[buf ^ 1][(3 * 256 + tid) >> 4][((3 * 256 + tid) & 15) * 4] = pf3;
            __syncthreads();
        }
    }
}

__global__ __launch_bounds__(256) void select_np(
    const unsigned* __restrict__ scw, const float* __restrict__ Vf,
    float* __restrict__ ctx, int U, int bh0)
{
#pragma clang fp contract(off)
    const int tid  = threadIdx.x;
    const int lane = tid & 63;
    const int wv   = tid >> 6;
    const int l0   = blockIdx.x * 8;
    const int bhl  = blockIdx.y;
    const int bh   = bh0 + bhl;
    const int b    = bh / NH;
    const int h    = bh % NH;

    __shared__ float wls[8][64];       // 2 KB
    __shared__ int   kls[8][64];       // 2 KB

    const unsigned long long laneLT = (1ull << lane) - 1ull;
    const float* __restrict__ Vb = Vf + (size_t)bh * LL * HD;

#pragma unroll
    for (int rr8 = 0; rr8 < 2; rr8++) {
        const int rr = wv * 2 + rr8;
        const unsigned* __restrict__ srow =
            scw + ((size_t)bhl * LL + l0 + rr) * LL;

        // own-lane scores, coalesced load; SHORT live range -> registers
        unsigned mv[32];
#pragma unroll
        for (int j = 0; j < 32; j++) mv[j] = srow[lane + 64 * j];

        // exact U-th-largest key (largest T with count(>=T) >= U)
        unsigned lo = 0u, hi = 0xFFFFFFFFu;
        while (lo < hi) {
            const unsigned span = hi - lo;
            const unsigned mid = lo + (span >> 1) + (span & 1u);
            int c = 0;
#pragma unroll
            for (int j = 0; j < 32; j++)
                c += (int)__popcll(__ballot(mv[j] >= mid));
            if (c >= U) lo = mid; else hi = mid - 1u;
        }

        // max kept (reduce in key domain; lanes w/o kept contribute 0)
        unsigned mk = 0;
#pragma unroll
        for (int j = 0; j < 32; j++)
            if (mv[j] >= lo) mk = (mv[j] > mk) ? mv[j] : mk;
#pragma unroll
        for (int off = 32; off > 0; off >>= 1) {
            const unsigned o = __shfl_xor(mk, off, 64);
            mk = (o > mk) ? o : mk;
        }
        const float mx = unmono32(mk);

        // compact kept (index order)
        int n = 0;
#pragma unroll
        for (int j = 0; j < 32; j++) {
            const bool p = (mv[j] >= lo);
            const unsigned long long ball = __ballot(p);
            if (p) {
                const int pos = n + (int)__popcll(ball & laneLT);
                if (pos < 64) {
                    kls[rr][pos] = lane + 64 * j;
                    wls[rr][pos] = expf(unmono32(mv[j]) - mx);
                }
            }
            n += (int)__popcll(ball);
        }
        if (n > 64) n = 64;

        float dl = (lane < n) ? wls[rr][lane] : 0.0f;
#pragma unroll
        for (int off = 32; off > 0; off >>= 1) dl += __shfl_xor(dl, off, 64);
        const float rden = 1.0f / dl;

        float acc = 0.0f;
        for (int c = 0; c < n; c++)
            acc = fmaf(wls[rr][c], Vb[(size_t)kls[rr][c] * HD + lane], acc);

        ctx[((size_t)b * LL + l0 + rr) * DM + h * HD + lane] = acc * rden;
    }
}

// ---------------------------------------------------------------------------
extern "C" void kernel_launch(void* const* d_in, const int* in_sizes, int n_in,
                              void* d_out, int out_size, void* d_ws, size_t ws_size,
                              hipStream_t stream)
{
    const float* x  = (const float*)d_in[0];
    const float* Wq = (const float*)d_in[1];
    const float* bq = (const float*)d_in[2];
    const float* Wk = (const float*)d_in[3];
    const float* bk = (const float*)d_in[4];
    const float* Wv = (const float*)d_in[5];
    const float* bv = (const float*)d_in[6];
    const float* Wo = (const float*)d_in[7];
    const float* bo = (const float*)d_in[8];
    float* out = (float*)d_out;

    const size_t E = (size_t)BB * NH * LL * HD;   // 4M elements
    float* Wt1 = (float*)d_ws;                    // 4 MB
    float* Wt2 = Wt1 + (size_t)DM * DM;           // 4 MB
    float* Qf  = Wt2 + (size_t)DM * DM;           // 16 MB
    float* Kf  = Qf + E;                          // 16 MB
    float* Vf  = Kf + E;                          // 16 MB
    float* ctx = Vf + E;                          // 16 MB   (72 MB total)
    unsigned* scw = (unsigned*)(ctx + E);         // scores chunks (<=128 MB)

    int U = (int)(5.0 * log((double)LL));
    if (U > LL) U = LL;

    // chunk size in (b,h) panels, bounded by remaining workspace
    const size_t base_bytes = (size_t)72 * 1024 * 1024;
    const size_t per_bh = (size_t)LL * LL * 4;    // 16 MB per panel
    size_t avail = (ws_size > base_bytes) ? (ws_size - base_bytes) : 0;
    int chunk = (int)(avail / per_bh);
    if (chunk < 1) chunk = 1;
    if (chunk > 8) chunk = 8;

    const int M = BB * LL;  // 4096
    dim3 blk(256);
    dim3 gT(DM / 32, DM / 32);
    dim3 gP(M / 8);
    dim3 g64(DM / 64, M / 64);

    hipLaunchKernelGGL(transpose1024, gT, blk, 0, stream, Wq, Wt1);
    hipLaunchKernelGGL(transpose1024, gT, blk, 0, stream, Wk, Wt2);
    hipLaunchKernelGGL(proj_emul, gP, blk, 0, stream, x, Wt1, bq, Qf);
    hipLaunchKernelGGL(proj_emul, gP, blk, 0, stream, x, Wt2, bk, Kf);
    hipLaunchKernelGGL((gemm_f32<0>), g64, blk, 0, stream, x, Wv, bv, Vf, M, DM, DM);

    for (int bh0 = 0; bh0 < BB * NH; bh0 += chunk) {
        int nb = BB * NH - bh0;
        if (nb > chunk) nb = chunk;
        dim3 gA(LL / 16, nb);
        dim3 gS(LL / 8, nb);
        hipLaunchKernelGGL(score_np,  gA, blk, 0, stream, Qf, Kf, scw, bh0);
        hipLaunchKernelGGL(select_np, gS, blk, 0, stream, scw, Vf, ctx, U, bh0);
    }

    hipLaunchKernelGGL((gemm_f32<1>), g64, blk, 0, stream, ctx, Wo, bo, out, M, DM, DM);
}

// Round 16
// 1633.696 us; speedup vs baseline: 1.0564x; 1.0564x over previous
//
#include <hip/hip_runtime.h>
#include <math.h>

#define BB 2
#define LL 2048
#define DM 1024
#define NH 16
#define HD 64

__device__ __forceinline__ unsigned mono32(float f) {
    unsigned u = __float_as_uint(f);
    return (u & 0x80000000u) ? ~u : (u | 0x80000000u);
}
__device__ __forceinline__ float unmono32(unsigned m) {
    const unsigned u = (m & 0x80000000u) ? (m & 0x7FFFFFFFu) : ~m;
    return __uint_as_float(u);
}

// ---------------------------------------------------------------------------
// 1024x1024 transpose: out[k][n] = in[n][k]
// ---------------------------------------------------------------------------
__global__ __launch_bounds__(256) void transpose1024(
    const float* __restrict__ in, float* __restrict__ out)
{
    __shared__ float t[32][33];
    const int bx = blockIdx.x * 32, by = blockIdx.y * 32;
    const int tx = threadIdx.x & 31, ty = threadIdx.x >> 5;
    for (int r = ty; r < 32; r += 8)
        t[r][tx] = in[(size_t)(by + r) * DM + bx + tx];
    __syncthreads();
    for (int r = ty; r < 32; r += 8)
        out[(size_t)(bx + r) * DM + by + tx] = t[tx][r];
}

// ---------------------------------------------------------------------------
// Bit-emulated f32 projection (numpy -> OpenBLAS sgemm, Zen/Haswell):
// K-panels (384,320,320); serial ascending-k FMA chain per panel; C += panel;
// then +bias. Scatter to [B,H,L,D]. Wt is W transposed [k][n].
// v2: 4 columns/thread (float4 W loads) + float4 LDS x reads; per-output
// fmaf chain IDENTICAL (k ascending per (m,n), panel C+= order kept).
// DO NOT TOUCH chain order: Q/K bit-exactness determines top-k selection.
// ---------------------------------------------------------------------------
__global__ __launch_bounds__(256) void proj_emul(
    const float* __restrict__ x, const float* __restrict__ Wt,
    const float* __restrict__ bias, float* __restrict__ outp)
{
    __shared__ float xs[8][DM];   // 32 KB
    const int tid = threadIdx.x;
    const int n4  = tid * 4;                 // 4 consecutive cols per thread
    const int m0  = blockIdx.x * 8;

    for (int i = tid; i < 8 * 256; i += 256) {
        const int r = i >> 8, c4 = (i & 255) << 2;
        *(float4*)&xs[r][c4] = *(const float4*)&x[(size_t)(m0 + r) * DM + c4];
    }
    __syncthreads();

    const int kbound[4] = {0, 384, 704, 1024};   // OpenBLAS Zen panel splits

    float S[8][4] = {};
#pragma unroll
    for (int p = 0; p < 3; p++) {
        float P[8][4] = {};
        for (int k = kbound[p]; k < kbound[p + 1]; k += 4) {
            const float4 w0 = *(const float4*)&Wt[(size_t)(k + 0) * DM + n4];
            const float4 w1 = *(const float4*)&Wt[(size_t)(k + 1) * DM + n4];
            const float4 w2 = *(const float4*)&Wt[(size_t)(k + 2) * DM + n4];
            const float4 w3 = *(const float4*)&Wt[(size_t)(k + 3) * DM + n4];
#pragma unroll
            for (int m = 0; m < 8; m++) {
                const float4 xv = *(const float4*)&xs[m][k];
                P[m][0] = fmaf(xv.x, w0.x, P[m][0]);
                P[m][1] = fmaf(xv.x, w0.y, P[m][1]);
                P[m][2] = fmaf(xv.x, w0.z, P[m][2]);
                P[m][3] = fmaf(xv.x, w0.w, P[m][3]);
                P[m][0] = fmaf(xv.y, w1.x, P[m][0]);
                P[m][1] = fmaf(xv.y, w1.y, P[m][1]);
                P[m][2] = fmaf(xv.y, w1.z, P[m][2]);
                P[m][3] = fmaf(xv.y, w1.w, P[m][3]);
                P[m][0] = fmaf(xv.z, w2.x, P[m][0]);
                P[m][1] = fmaf(xv.z, w2.y, P[m][1]);
                P[m][2] = fmaf(xv.z, w2.z, P[m][2]);
                P[m][3] = fmaf(xv.z, w2.w, P[m][3]);
                P[m][0] = fmaf(xv.w, w3.x, P[m][0]);
                P[m][1] = fmaf(xv.w, w3.y, P[m][1]);
                P[m][2] = fmaf(xv.w, w3.z, P[m][2]);
                P[m][3] = fmaf(xv.w, w3.w, P[m][3]);
            }
        }
#pragma unroll
        for (int m = 0; m < 8; m++) {
#pragma unroll
            for (int j = 0; j < 4; j++) S[m][j] += P[m][j];  // C += panel
        }
    }

    const float4 b4v = *(const float4*)&bias[n4];
    const int h = n4 / HD, d0 = n4 % HD;   // 4 cols stay in one head
#pragma unroll
    for (int m = 0; m < 8; m++) {
        const int mm = m0 + m;
        const int b = mm / LL, l = mm % LL;
        float4 o;
        o.x = S[m][0] + b4v.x; o.y = S[m][1] + b4v.y;
        o.z = S[m][2] + b4v.z; o.w = S[m][3] + b4v.w;
        *(float4*)&outp[(((size_t)b * NH + h) * LL + l) * HD + d0] = o;
    }
}

// ---------------------------------------------------------------------------
// f32 GEMM for V (MODE 0 scatter) and output projection (MODE 1).
// ---------------------------------------------------------------------------
template <int MODE>
__global__ __launch_bounds__(256) void gemm_f32(
    const float* __restrict__ A, const float* __restrict__ W,
    const float* __restrict__ bias, float* __restrict__ out,
    int M, int N, int K)
{
    __shared__ float As[16][64];
    __shared__ float Bs[16][64];
    const int tid = threadIdx.x;
    const int m0 = blockIdx.y * 64;
    const int n0 = blockIdx.x * 64;
    const int tx = tid & 15, ty = tid >> 4;
    const int lr = tid >> 2, lc = (tid & 3) * 4;

    float acc[4][4] = {};

    for (int k0 = 0; k0 < K; k0 += 16) {
        float4 a4 = *(const float4*)&A[(size_t)(m0 + lr) * K + k0 + lc];
        float4 b4 = *(const float4*)&W[(size_t)(n0 + lr) * K + k0 + lc];
        __syncthreads();
        As[lc + 0][lr] = a4.x; As[lc + 1][lr] = a4.y;
        As[lc + 2][lr] = a4.z; As[lc + 3][lr] = a4.w;
        Bs[lc + 0][lr] = b4.x; Bs[lc + 1][lr] = b4.y;
        Bs[lc + 2][lr] = b4.z; Bs[lc + 3][lr] = b4.w;
        __syncthreads();
#pragma unroll
        for (int kk = 0; kk < 16; kk++) {
            float4 av = *(const float4*)&As[kk][ty * 4];
            float4 bv = *(const float4*)&Bs[kk][tx * 4];
            float a[4] = {av.x, av.y, av.z, av.w};
            float b[4] = {bv.x, bv.y, bv.z, bv.w};
#pragma unroll
            for (int i = 0; i < 4; i++)
#pragma unroll
                for (int j = 0; j < 4; j++)
                    acc[i][j] = fmaf(a[i], b[j], acc[i][j]);
        }
    }

#pragma unroll
    for (int i = 0; i < 4; i++) {
        const int m = m0 + ty * 4 + i;
#pragma unroll
        for (int j = 0; j < 4; j++) {
            const int n = n0 + tx * 4 + j;
            const float v = acc[i][j] + bias[n];
            if (MODE == 0) {
                const int b = m / LL, l = m % LL;
                const int h = n / HD, d = n % HD;
                out[(((size_t)b * NH + h) * LL + l) * HD + d] = v;
            } else {
                out[(size_t)m * N + n] = v;
            }
        }
    }
}

// ---------------------------------------------------------------------------
// Attention: score_np (producer) + select_np (consumer); split (R7) killed
// the structural 64-reg live range that spilled in v3-v6.
//
// score_np: R12-proven v2 (181 µs/launch-per-8-panels, VGPR 80, zero
//   scratch). FINAL after probing every q-path variant:
//   - wider per-lane work (R9/R10/R11): spills — ~80-100 VGPR live-state
//     wall for this loop shape, regardless of launch_bounds hints.
//   - q from global via uniform base (R15): 207 µs — uniform addresses
//     still go through per-lane VMEM loads; LDS broadcast is cheaper.
//   - q in SGPRs: 64 floats/row exceeds the SGPR budget.
//   v2: 4 q-rows/wave, double-buffered 64-key tiles, named pf0-3 prefetch,
//   idx-coalesced staging, single barrier per tile. DO NOT rewiden.
// select_np: R0-proven consumer; mv[32] short live range -> registers.
// ---------------------------------------------------------------------------
__global__ __launch_bounds__(256) void score_np(
    const float* __restrict__ Qf, const float* __restrict__ Kf,
    unsigned* __restrict__ scw, int bh0)
{
#pragma clang fp contract(off)
    const int tid  = threadIdx.x;
    const int lane = tid & 63;
    const int wv   = tid >> 6;
    const int l0   = blockIdx.x * 16;
    const int bhl  = blockIdx.y;
    const int bh   = bh0 + bhl;

    __shared__ float kt[2][64][68];    // 34 KB K tiles (+4 pad per row)
    __shared__ float qsh[16][64];      // 4 KB

    const float* __restrict__ Kb = Kf + (size_t)bh * LL * HD;

    // stage q rows: 256 threads = 16 rows x 16 float4, one each
    {
        const int r = tid >> 4, d4q = tid & 15;
        *(float4*)&qsh[r][d4q * 4] =
            *(const float4*)&Qf[((size_t)bh * LL + l0 + r) * HD + d4q * 4];
    }
    // stage K tile 0 (64 rows x 16 float4; coalesced)
#pragma unroll
    for (int i = 0; i < 4; i++) {
        const int idx = i * 256 + tid;
        *(float4*)&kt[0][idx >> 4][(idx & 15) * 4] =
            *(const float4*)&Kb[(size_t)(idx >> 4) * HD + (idx & 15) * 4];
    }
    __syncthreads();

    const int r0 = wv * 4;
    unsigned* __restrict__ s0 = scw + ((size_t)bhl * LL + l0 + r0 + 0) * LL;
    unsigned* __restrict__ s1 = scw + ((size_t)bhl * LL + l0 + r0 + 1) * LL;
    unsigned* __restrict__ s2 = scw + ((size_t)bhl * LL + l0 + r0 + 2) * LL;
    unsigned* __restrict__ s3 = scw + ((size_t)bhl * LL + l0 + r0 + 3) * LL;

    for (int tile = 0; tile < 32; tile++) {
        const int buf = tile & 1;
        float4 pf0, pf1, pf2, pf3;
        if (tile < 31) {
            const float* src = Kb + (size_t)(tile + 1) * 64 * HD;
            pf0 = *(const float4*)&src[(size_t)((0 * 256 + tid) >> 4) * HD + ((0 * 256 + tid) & 15) * 4];
            pf1 = *(const float4*)&src[(size_t)((1 * 256 + tid) >> 4) * HD + ((1 * 256 + tid) & 15) * 4];
            pf2 = *(const float4*)&src[(size_t)((2 * 256 + tid) >> 4) * HD + ((2 * 256 + tid) & 15) * 4];
            pf3 = *(const float4*)&src[(size_t)((3 * 256 + tid) >> 4) * HD + ((3 * 256 + tid) & 15) * 4];
        }

        // scores for key = tile*64 + lane, rows r0..r0+3 (bit-exact chains,
        // independent per row; per-row op order identical)
        float ax0 = 0, ay0 = 0, az0 = 0, aw0 = 0;
        float ax1 = 0, ay1 = 0, az1 = 0, aw1 = 0;
        float ax2 = 0, ay2 = 0, az2 = 0, aw2 = 0;
        float ax3 = 0, ay3 = 0, az3 = 0, aw3 = 0;
        const float* krow = &kt[buf][lane][0];
        const float* q0 = &qsh[r0 + 0][0];
        const float* q1 = &qsh[r0 + 1][0];
        const float* q2 = &qsh[r0 + 2][0];
        const float* q3 = &qsh[r0 + 3][0];
#pragma unroll
        for (int t = 0; t < 4; t++) {
#pragma unroll
            for (int sub = 3; sub >= 0; sub--) {
                const int d4 = 4 * t + sub;
                const float4 kf = *(const float4*)&krow[d4 * 4];
                const float4 qa = *(const float4*)&q0[d4 * 4];
                const float4 qb = *(const float4*)&q1[d4 * 4];
                const float4 qc = *(const float4*)&q2[d4 * 4];
                const float4 qd = *(const float4*)&q3[d4 * 4];
                ax0 = qa.x * kf.x + ax0; ay0 = qa.y * kf.y + ay0;
                az0 = qa.z * kf.z + az0; aw0 = qa.w * kf.w + aw0;
                ax1 = qb.x * kf.x + ax1; ay1 = qb.y * kf.y + ay1;
                az1 = qb.z * kf.z + az1; aw1 = qb.w * kf.w + aw1;
                ax2 = qc.x * kf.x + ax2; ay2 = qc.y * kf.y + ay2;
                az2 = qc.z * kf.z + az2; aw2 = qc.w * kf.w + aw2;
                ax3 = qd.x * kf.x + ax3; ay3 = qd.y * kf.y + ay3;
                az3 = qd.z * kf.z + az3; aw3 = qd.w * kf.w + aw3;
            }
        }
        // immediate coalesced stores (lane-consecutive u32), no live range
        s0[tile * 64 + lane] = mono32(((ax0 + ay0) + (az0 + aw0)) * 0.125f);
        s1[tile * 64 + lane] = mono32(((ax1 + ay1) + (az1 + aw1)) * 0.125f);
        s2[tile * 64 + lane] = mono32(((ax2 + ay2) + (az2 + aw2)) * 0.125f);
        s3[tile * 64 + lane] = mono32(((ax3 + ay3) + (az3 + aw3)) * 0.125f);

        if (tile < 31) {
            // single barrier per tile: reads kt[buf] / writes kt[buf^1]
            // are disjoint buffers.
            *(float4*)&kt[buf ^ 1][(0 * 256 + tid) >> 4][((0 * 256 + tid) & 15) * 4] = pf0;
            *(float4*)&kt[buf ^ 1][(1 * 256 + tid) >> 4][((1 * 256 + tid) & 15) * 4] = pf1;
            *(float4*)&kt[buf ^ 1][(2 * 256 + tid) >> 4][((2 * 256 + tid) & 15) * 4] = pf2;
            *(float4*)&kt[buf ^ 1][(3 * 256 + tid) >> 4][((3 * 256 + tid) & 15) * 4] = pf3;
            __syncthreads();
        }
    }
}

__global__ __launch_bounds__(256) void select_np(
    const unsigned* __restrict__ scw, const float* __restrict__ Vf,
    float* __restrict__ ctx, int U, int bh0)
{
#pragma clang fp contract(off)
    const int tid  = threadIdx.x;
    const int lane = tid & 63;
    const int wv   = tid >> 6;
    const int l0   = blockIdx.x * 8;
    const int bhl  = blockIdx.y;
    const int bh   = bh0 + bhl;
    const int b    = bh / NH;
    const int h    = bh % NH;

    __shared__ float wls[8][64];       // 2 KB
    __shared__ int   kls[8][64];       // 2 KB

    const unsigned long long laneLT = (1ull << lane) - 1ull;
    const float* __restrict__ Vb = Vf + (size_t)bh * LL * HD;

#pragma unroll
    for (int rr8 = 0; rr8 < 2; rr8++) {
        const int rr = wv * 2 + rr8;
        const unsigned* __restrict__ srow =
            scw + ((size_t)bhl * LL + l0 + rr) * LL;

        // own-lane scores, coalesced load; SHORT live range -> registers
        unsigned mv[32];
#pragma unroll
        for (int j = 0; j < 32; j++) mv[j] = srow[lane + 64 * j];

        // exact U-th-largest key (largest T with count(>=T) >= U)
        unsigned lo = 0u, hi = 0xFFFFFFFFu;
        while (lo < hi) {
            const unsigned span = hi - lo;
            const unsigned mid = lo + (span >> 1) + (span & 1u);
            int c = 0;
#pragma unroll
            for (int j = 0; j < 32; j++)
                c += (int)__popcll(__ballot(mv[j] >= mid));
            if (c >= U) lo = mid; else hi = mid - 1u;
        }

        // max kept (reduce in key domain; lanes w/o kept contribute 0)
        unsigned mk = 0;
#pragma unroll
        for (int j = 0; j < 32; j++)
            if (mv[j] >= lo) mk = (mv[j] > mk) ? mv[j] : mk;
#pragma unroll
        for (int off = 32; off > 0; off >>= 1) {
            const unsigned o = __shfl_xor(mk, off, 64);
            mk = (o > mk) ? o : mk;
        }
        const float mx = unmono32(mk);

        // compact kept (index order)
        int n = 0;
#pragma unroll
        for (int j = 0; j < 32; j++) {
            const bool p = (mv[j] >= lo);
            const unsigned long long ball = __ballot(p);
            if (p) {
                const int pos = n + (int)__popcll(ball & laneLT);
                if (pos < 64) {
                    kls[rr][pos] = lane + 64 * j;
                    wls[rr][pos] = expf(unmono32(mv[j]) - mx);
                }
            }
            n += (int)__popcll(ball);
        }
        if (n > 64) n = 64;

        float dl = (lane < n) ? wls[rr][lane] : 0.0f;
#pragma unroll
        for (int off = 32; off > 0; off >>= 1) dl += __shfl_xor(dl, off, 64);
        const float rden = 1.0f / dl;

        float acc = 0.0f;
        for (int c = 0; c < n; c++)
            acc = fmaf(wls[rr][c], Vb[(size_t)kls[rr][c] * HD + lane], acc);

        ctx[((size_t)b * LL + l0 + rr) * DM + h * HD + lane] = acc * rden;
    }
}

// ---------------------------------------------------------------------------
extern "C" void kernel_launch(void* const* d_in, const int* in_sizes, int n_in,
                              void* d_out, int out_size, void* d_ws, size_t ws_size,
                              hipStream_t stream)
{
    const float* x  = (const float*)d_in[0];
    const float* Wq = (const float*)d_in[1];
    const float* bq = (const float*)d_in[2];
    const float* Wk = (const float*)d_in[3];
    const float* bk = (const float*)d_in[4];
    const float* Wv = (const float*)d_in[5];
    const float* bv = (const float*)d_in[6];
    const float* Wo = (const float*)d_in[7];
    const float* bo = (const float*)d_in[8];
    float* out = (float*)d_out;

    const size_t E = (size_t)BB * NH * LL * HD;   // 4M elements
    float* Wt1 = (float*)d_ws;                    // 4 MB
    float* Wt2 = Wt1 + (size_t)DM * DM;           // 4 MB
    float* Qf  = Wt2 + (size_t)DM * DM;           // 16 MB
    float* Kf  = Qf + E;                          // 16 MB
    float* Vf  = Kf + E;                          // 16 MB
    float* ctx = Vf + E;                          // 16 MB   (72 MB total)
    unsigned* scw = (unsigned*)(ctx + E);         // scores chunks (<=256 MB)

    int U = (int)(5.0 * log((double)LL));
    if (U > LL) U = LL;

    // chunk size in (b,h) panels, bounded by remaining workspace
    const size_t base_bytes = (size_t)72 * 1024 * 1024;
    const size_t per_bh = (size_t)LL * LL * 4;    // 16 MB per panel
    size_t avail = (ws_size > base_bytes) ? (ws_size - base_bytes) : 0;
    int chunk = (int)(avail / per_bh);
    if (chunk < 1) chunk = 1;
    if (chunk > 16) chunk = 16;   // R16: cap raised 8->16 (fewer launches,
                                  // better tail utilization; ws-guarded)

    const int M = BB * LL;  // 4096
    dim3 blk(256);
    dim3 gT(DM / 32, DM / 32);
    dim3 gP(M / 8);
    dim3 g64(DM / 64, M / 64);

    hipLaunchKernelGGL(transpose1024, gT, blk, 0, stream, Wq, Wt1);
    hipLaunchKernelGGL(transpose1024, gT, blk, 0, stream, Wk, Wt2);
    hipLaunchKernelGGL(proj_emul, gP, blk, 0, stream, x, Wt1, bq, Qf);
    hipLaunchKernelGGL(proj_emul, gP, blk, 0, stream, x, Wt2, bk, Kf);
    hipLaunchKernelGGL((gemm_f32<0>), g64, blk, 0, stream, x, Wv, bv, Vf, M, DM, DM);

    for (int bh0 = 0; bh0 < BB * NH; bh0 += chunk) {
        int nb = BB * NH - bh0;
        if (nb > chunk) nb = chunk;
        dim3 gA(LL / 16, nb);
        dim3 gS(LL / 8, nb);
        hipLaunchKernelGGL(score_np,  gA, blk, 0, stream, Qf, Kf, scw, bh0);
        hipLaunchKernelGGL(select_np, gS, blk, 0, stream, scw, Vf, ctx, U, bh0);
    }

    hipLaunchKernelGGL((gemm_f32<1>), g64, blk, 0, stream, ctx, Wo, bo, out, M, DM, DM);
}

// Round 17
// 1609.212 us; speedup vs baseline: 1.0724x; 1.0152x over previous
//
#include <hip/hip_runtime.h>
#include <math.h>

#define BB 2
#define LL 2048
#define DM 1024
#define NH 16
#define HD 64

__device__ __forceinline__ unsigned mono32(float f) {
    unsigned u = __float_as_uint(f);
    return (u & 0x80000000u) ? ~u : (u | 0x80000000u);
}
__device__ __forceinline__ float unmono32(unsigned m) {
    const unsigned u = (m & 0x80000000u) ? (m & 0x7FFFFFFFu) : ~m;
    return __uint_as_float(u);
}

// ---------------------------------------------------------------------------
// 1024x1024 transpose: out[k][n] = in[n][k]
// ---------------------------------------------------------------------------
__global__ __launch_bounds__(256) void transpose1024(
    const float* __restrict__ in, float* __restrict__ out)
{
    __shared__ float t[32][33];
    const int bx = blockIdx.x * 32, by = blockIdx.y * 32;
    const int tx = threadIdx.x & 31, ty = threadIdx.x >> 5;
    for (int r = ty; r < 32; r += 8)
        t[r][tx] = in[(size_t)(by + r) * DM + bx + tx];
    __syncthreads();
    for (int r = ty; r < 32; r += 8)
        out[(size_t)(bx + r) * DM + by + tx] = t[tx][r];
}

// ---------------------------------------------------------------------------
// Bit-emulated f32 projection (numpy -> OpenBLAS sgemm, Zen/Haswell):
// K-panels (384,320,320); serial ascending-k FMA chain per panel; C += panel;
// then +bias. Scatter to [B,H,L,D]. Wt is W transposed [k][n].
// v2: 4 columns/thread (float4 W loads) + float4 LDS x reads; per-output
// fmaf chain IDENTICAL (k ascending per (m,n), panel C+= order kept).
// DO NOT TOUCH chain order: Q/K bit-exactness determines top-k selection.
// ---------------------------------------------------------------------------
__global__ __launch_bounds__(256) void proj_emul(
    const float* __restrict__ x, const float* __restrict__ Wt,
    const float* __restrict__ bias, float* __restrict__ outp)
{
    __shared__ float xs[8][DM];   // 32 KB
    const int tid = threadIdx.x;
    const int n4  = tid * 4;                 // 4 consecutive cols per thread
    const int m0  = blockIdx.x * 8;

    for (int i = tid; i < 8 * 256; i += 256) {
        const int r = i >> 8, c4 = (i & 255) << 2;
        *(float4*)&xs[r][c4] = *(const float4*)&x[(size_t)(m0 + r) * DM + c4];
    }
    __syncthreads();

    const int kbound[4] = {0, 384, 704, 1024};   // OpenBLAS Zen panel splits

    float S[8][4] = {};
#pragma unroll
    for (int p = 0; p < 3; p++) {
        float P[8][4] = {};
        for (int k = kbound[p]; k < kbound[p + 1]; k += 4) {
            const float4 w0 = *(const float4*)&Wt[(size_t)(k + 0) * DM + n4];
            const float4 w1 = *(const float4*)&Wt[(size_t)(k + 1) * DM + n4];
            const float4 w2 = *(const float4*)&Wt[(size_t)(k + 2) * DM + n4];
            const float4 w3 = *(const float4*)&Wt[(size_t)(k + 3) * DM + n4];
#pragma unroll
            for (int m = 0; m < 8; m++) {
                const float4 xv = *(const float4*)&xs[m][k];
                P[m][0] = fmaf(xv.x, w0.x, P[m][0]);
                P[m][1] = fmaf(xv.x, w0.y, P[m][1]);
                P[m][2] = fmaf(xv.x, w0.z, P[m][2]);
                P[m][3] = fmaf(xv.x, w0.w, P[m][3]);
                P[m][0] = fmaf(xv.y, w1.x, P[m][0]);
                P[m][1] = fmaf(xv.y, w1.y, P[m][1]);
                P[m][2] = fmaf(xv.y, w1.z, P[m][2]);
                P[m][3] = fmaf(xv.y, w1.w, P[m][3]);
                P[m][0] = fmaf(xv.z, w2.x, P[m][0]);
                P[m][1] = fmaf(xv.z, w2.y, P[m][1]);
                P[m][2] = fmaf(xv.z, w2.z, P[m][2]);
                P[m][3] = fmaf(xv.z, w2.w, P[m][3]);
                P[m][0] = fmaf(xv.w, w3.x, P[m][0]);
                P[m][1] = fmaf(xv.w, w3.y, P[m][1]);
                P[m][2] = fmaf(xv.w, w3.z, P[m][2]);
                P[m][3] = fmaf(xv.w, w3.w, P[m][3]);
            }
        }
#pragma unroll
        for (int m = 0; m < 8; m++) {
#pragma unroll
            for (int j = 0; j < 4; j++) S[m][j] += P[m][j];  // C += panel
        }
    }

    const float4 b4v = *(const float4*)&bias[n4];
    const int h = n4 / HD, d0 = n4 % HD;   // 4 cols stay in one head
#pragma unroll
    for (int m = 0; m < 8; m++) {
        const int mm = m0 + m;
        const int b = mm / LL, l = mm % LL;
        float4 o;
        o.x = S[m][0] + b4v.x; o.y = S[m][1] + b4v.y;
        o.z = S[m][2] + b4v.z; o.w = S[m][3] + b4v.w;
        *(float4*)&outp[(((size_t)b * NH + h) * LL + l) * HD + d0] = o;
    }
}

// ---------------------------------------------------------------------------
// f32 GEMM for V (MODE 0 scatter) and output projection (MODE 1).
// ---------------------------------------------------------------------------
template <int MODE>
__global__ __launch_bounds__(256) void gemm_f32(
    const float* __restrict__ A, const float* __restrict__ W,
    const float* __restrict__ bias, float* __restrict__ out,
    int M, int N, int K)
{
    __shared__ float As[16][64];
    __shared__ float Bs[16][64];
    const int tid = threadIdx.x;
    const int m0 = blockIdx.y * 64;
    const int n0 = blockIdx.x * 64;
    const int tx = tid & 15, ty = tid >> 4;
    const int lr = tid >> 2, lc = (tid & 3) * 4;

    float acc[4][4] = {};

    for (int k0 = 0; k0 < K; k0 += 16) {
        float4 a4 = *(const float4*)&A[(size_t)(m0 + lr) * K + k0 + lc];
        float4 b4 = *(const float4*)&W[(size_t)(n0 + lr) * K + k0 + lc];
        __syncthreads();
        As[lc + 0][lr] = a4.x; As[lc + 1][lr] = a4.y;
        As[lc + 2][lr] = a4.z; As[lc + 3][lr] = a4.w;
        Bs[lc + 0][lr] = b4.x; Bs[lc + 1][lr] = b4.y;
        Bs[lc + 2][lr] = b4.z; Bs[lc + 3][lr] = b4.w;
        __syncthreads();
#pragma unroll
        for (int kk = 0; kk < 16; kk++) {
            float4 av = *(const float4*)&As[kk][ty * 4];
            float4 bv = *(const float4*)&Bs[kk][tx * 4];
            float a[4] = {av.x, av.y, av.z, av.w};
            float b[4] = {bv.x, bv.y, bv.z, bv.w};
#pragma unroll
            for (int i = 0; i < 4; i++)
#pragma unroll
                for (int j = 0; j < 4; j++)
                    acc[i][j] = fmaf(a[i], b[j], acc[i][j]);
        }
    }

#pragma unroll
    for (int i = 0; i < 4; i++) {
        const int m = m0 + ty * 4 + i;
#pragma unroll
        for (int j = 0; j < 4; j++) {
            const int n = n0 + tx * 4 + j;
            const float v = acc[i][j] + bias[n];
            if (MODE == 0) {
                const int b = m / LL, l = m % LL;
                const int h = n / HD, d = n % HD;
                out[(((size_t)b * NH + h) * LL + l) * HD + d] = v;
            } else {
                out[(size_t)m * N + n] = v;
            }
        }
    }
}

// ---------------------------------------------------------------------------
// Attention: score_np (producer) + select_np (consumer); split (R7) killed
// the structural 64-reg live range that spilled in v3-v6.
//
// score_np v7 (R17): single-buffered kt[64][68] (LDS 21.5 KB, was 38.9 KB
//   double-buffered) + 2 barriers/tile. The pf0-3 REGISTER prefetch (v2-
//   proven) still hides HBM latency; the double-buffer only saved one
//   barrier while capping residency at ~2 blocks/CU (VALUBusy 65%, 35%
//   barrier/latency idle). Single buffer -> ~6 blocks/CU co-resident
//   (LDS allows 7, VGPR 80 allows 6): barrier-stalled blocks overlap
//   other blocks' compute. Chain values/order IDENTICAL -> bit-exact.
//   [Ledger: per-lane widening spills (R9-11); uniform-global q slower
//   (R15); q-in-SGPR exceeds budget. DO NOT rewiden.]
// select_np: R0-proven consumer; mv[32] short live range -> registers.
// ---------------------------------------------------------------------------
__global__ __launch_bounds__(256) void score_np(
    const float* __restrict__ Qf, const float* __restrict__ Kf,
    unsigned* __restrict__ scw, int bh0)
{
#pragma clang fp contract(off)
    const int tid  = threadIdx.x;
    const int lane = tid & 63;
    const int wv   = tid >> 6;
    const int l0   = blockIdx.x * 16;
    const int bhl  = blockIdx.y;
    const int bh   = bh0 + bhl;

    __shared__ float kt[64][68];       // 17 KB: 64 K-rows (+4 pad per row)
    __shared__ float qsh[16][64];      // 4 KB

    const float* __restrict__ Kb = Kf + (size_t)bh * LL * HD;

    // stage q rows: 256 threads = 16 rows x 16 float4, one each
    {
        const int r = tid >> 4, d4q = tid & 15;
        *(float4*)&qsh[r][d4q * 4] =
            *(const float4*)&Qf[((size_t)bh * LL + l0 + r) * HD + d4q * 4];
    }
    // stage K tile 0 (64 rows x 16 float4; coalesced)
#pragma unroll
    for (int i = 0; i < 4; i++) {
        const int idx = i * 256 + tid;
        *(float4*)&kt[idx >> 4][(idx & 15) * 4] =
            *(const float4*)&Kb[(size_t)(idx >> 4) * HD + (idx & 15) * 4];
    }
    __syncthreads();

    const int r0 = wv * 4;
    unsigned* __restrict__ s0 = scw + ((size_t)bhl * LL + l0 + r0 + 0) * LL;
    unsigned* __restrict__ s1 = scw + ((size_t)bhl * LL + l0 + r0 + 1) * LL;
    unsigned* __restrict__ s2 = scw + ((size_t)bhl * LL + l0 + r0 + 2) * LL;
    unsigned* __restrict__ s3 = scw + ((size_t)bhl * LL + l0 + r0 + 3) * LL;

    for (int tile = 0; tile < 32; tile++) {
        float4 pf0, pf1, pf2, pf3;
        if (tile < 31) {
            const float* src = Kb + (size_t)(tile + 1) * 64 * HD;
            pf0 = *(const float4*)&src[(size_t)((0 * 256 + tid) >> 4) * HD + ((0 * 256 + tid) & 15) * 4];
            pf1 = *(const float4*)&src[(size_t)((1 * 256 + tid) >> 4) * HD + ((1 * 256 + tid) & 15) * 4];
            pf2 = *(const float4*)&src[(size_t)((2 * 256 + tid) >> 4) * HD + ((2 * 256 + tid) & 15) * 4];
            pf3 = *(const float4*)&src[(size_t)((3 * 256 + tid) >> 4) * HD + ((3 * 256 + tid) & 15) * 4];
        }

        // scores for key = tile*64 + lane, rows r0..r0+3 (bit-exact chains,
        // independent per row; per-row op order identical)
        float ax0 = 0, ay0 = 0, az0 = 0, aw0 = 0;
        float ax1 = 0, ay1 = 0, az1 = 0, aw1 = 0;
        float ax2 = 0, ay2 = 0, az2 = 0, aw2 = 0;
        float ax3 = 0, ay3 = 0, az3 = 0, aw3 = 0;
        const float* krow = &kt[lane][0];
        const float* q0 = &qsh[r0 + 0][0];
        const float* q1 = &qsh[r0 + 1][0];
        const float* q2 = &qsh[r0 + 2][0];
        const float* q3 = &qsh[r0 + 3][0];
#pragma unroll
        for (int t = 0; t < 4; t++) {
#pragma unroll
            for (int sub = 3; sub >= 0; sub--) {
                const int d4 = 4 * t + sub;
                const float4 kf = *(const float4*)&krow[d4 * 4];
                const float4 qa = *(const float4*)&q0[d4 * 4];
                const float4 qb = *(const float4*)&q1[d4 * 4];
                const float4 qc = *(const float4*)&q2[d4 * 4];
                const float4 qd = *(const float4*)&q3[d4 * 4];
                ax0 = qa.x * kf.x + ax0; ay0 = qa.y * kf.y + ay0;
                az0 = qa.z * kf.z + az0; aw0 = qa.w * kf.w + aw0;
                ax1 = qb.x * kf.x + ax1; ay1 = qb.y * kf.y + ay1;
                az1 = qb.z * kf.z + az1; aw1 = qb.w * kf.w + aw1;
                ax2 = qc.x * kf.x + ax2; ay2 = qc.y * kf.y + ay2;
                az2 = qc.z * kf.z + az2; aw2 = qc.w * kf.w + aw2;
                ax3 = qd.x * kf.x + ax3; ay3 = qd.y * kf.y + ay3;
                az3 = qd.z * kf.z + az3; aw3 = qd.w * kf.w + aw3;
            }
        }
        // immediate coalesced stores (lane-consecutive u32), no live range
        s0[tile * 64 + lane] = mono32(((ax0 + ay0) + (az0 + aw0)) * 0.125f);
        s1[tile * 64 + lane] = mono32(((ax1 + ay1) + (az1 + aw1)) * 0.125f);
        s2[tile * 64 + lane] = mono32(((ax2 + ay2) + (az2 + aw2)) * 0.125f);
        s3[tile * 64 + lane] = mono32(((ax3 + ay3) + (az3 + aw3)) * 0.125f);

        if (tile < 31) {
            __syncthreads();   // all reads of kt for this tile done
            *(float4*)&kt[(0 * 256 + tid) >> 4][((0 * 256 + tid) & 15) * 4] = pf0;
            *(float4*)&kt[(1 * 256 + tid) >> 4][((1 * 256 + tid) & 15) * 4] = pf1;
            *(float4*)&kt[(2 * 256 + tid) >> 4][((2 * 256 + tid) & 15) * 4] = pf2;
            *(float4*)&kt[(3 * 256 + tid) >> 4][((3 * 256 + tid) & 15) * 4] = pf3;
            __syncthreads();   // kt ready for next tile
        }
    }
}

__global__ __launch_bounds__(256) void select_np(
    const unsigned* __restrict__ scw, const float* __restrict__ Vf,
    float* __restrict__ ctx, int U, int bh0)
{
#pragma clang fp contract(off)
    const int tid  = threadIdx.x;
    const int lane = tid & 63;
    const int wv   = tid >> 6;
    const int l0   = blockIdx.x * 8;
    const int bhl  = blockIdx.y;
    const int bh   = bh0 + bhl;
    const int b    = bh / NH;
    const int h    = bh % NH;

    __shared__ float wls[8][64];       // 2 KB
    __shared__ int   kls[8][64];       // 2 KB

    const unsigned long long laneLT = (1ull << lane) - 1ull;
    const float* __restrict__ Vb = Vf + (size_t)bh * LL * HD;

#pragma unroll
    for (int rr8 = 0; rr8 < 2; rr8++) {
        const int rr = wv * 2 + rr8;
        const unsigned* __restrict__ srow =
            scw + ((size_t)bhl * LL + l0 + rr) * LL;

        // own-lane scores, coalesced load; SHORT live range -> registers
        unsigned mv[32];
#pragma unroll
        for (int j = 0; j < 32; j++) mv[j] = srow[lane + 64 * j];

        // exact U-th-largest key (largest T with count(>=T) >= U)
        unsigned lo = 0u, hi = 0xFFFFFFFFu;
        while (lo < hi) {
            const unsigned span = hi - lo;
            const unsigned mid = lo + (span >> 1) + (span & 1u);
            int c = 0;
#pragma unroll
            for (int j = 0; j < 32; j++)
                c += (int)__popcll(__ballot(mv[j] >= mid));
            if (c >= U) lo = mid; else hi = mid - 1u;
        }

        // max kept (reduce in key domain; lanes w/o kept contribute 0)
        unsigned mk = 0;
#pragma unroll
        for (int j = 0; j < 32; j++)
            if (mv[j] >= lo) mk = (mv[j] > mk) ? mv[j] : mk;
#pragma unroll
        for (int off = 32; off > 0; off >>= 1) {
            const unsigned o = __shfl_xor(mk, off, 64);
            mk = (o > mk) ? o : mk;
        }
        const float mx = unmono32(mk);

        // compact kept (index order)
        int n = 0;
#pragma unroll
        for (int j = 0; j < 32; j++) {
            const bool p = (mv[j] >= lo);
            const unsigned long long ball = __ballot(p);
            if (p) {
                const int pos = n + (int)__popcll(ball & laneLT);
                if (pos < 64) {
                    kls[rr][pos] = lane + 64 * j;
                    wls[rr][pos] = expf(unmono32(mv[j]) - mx);
                }
            }
            n += (int)__popcll(ball);
        }
        if (n > 64) n = 64;

        float dl = (lane < n) ? wls[rr][lane] : 0.0f;
#pragma unroll
        for (int off = 32; off > 0; off >>= 1) dl += __shfl_xor(dl, off, 64);
        const float rden = 1.0f / dl;

        float acc = 0.0f;
        for (int c = 0; c < n; c++)
            acc = fmaf(wls[rr][c], Vb[(size_t)kls[rr][c] * HD + lane], acc);

        ctx[((size_t)b * LL + l0 + rr) * DM + h * HD + lane] = acc * rden;
    }
}

// ---------------------------------------------------------------------------
extern "C" void kernel_launch(void* const* d_in, const int* in_sizes, int n_in,
                              void* d_out, int out_size, void* d_ws, size_t ws_size,
                              hipStream_t stream)
{
    const float* x  = (const float*)d_in[0];
    const float* Wq = (const float*)d_in[1];
    const float* bq = (const float*)d_in[2];
    const float* Wk = (const float*)d_in[3];
    const float* bk = (const float*)d_in[4];
    const float* Wv = (const float*)d_in[5];
    const float* bv = (const float*)d_in[6];
    const float* Wo = (const float*)d_in[7];
    const float* bo = (const float*)d_in[8];
    float* out = (float*)d_out;

    const size_t E = (size_t)BB * NH * LL * HD;   // 4M elements
    float* Wt1 = (float*)d_ws;                    // 4 MB
    float* Wt2 = Wt1 + (size_t)DM * DM;           // 4 MB
    float* Qf  = Wt2 + (size_t)DM * DM;           // 16 MB
    float* Kf  = Qf + E;                          // 16 MB
    float* Vf  = Kf + E;                          // 16 MB
    float* ctx = Vf + E;                          // 16 MB   (72 MB total)
    unsigned* scw = (unsigned*)(ctx + E);         // scores chunks

    int U = (int)(5.0 * log((double)LL));
    if (U > LL) U = LL;

    // chunk size in (b,h) panels, bounded by remaining workspace
    const size_t base_bytes = (size_t)72 * 1024 * 1024;
    const size_t per_bh = (size_t)LL * LL * 4;    // 16 MB per panel
    size_t avail = (ws_size > base_bytes) ? (ws_size - base_bytes) : 0;
    int chunk = (int)(avail / per_bh);
    if (chunk < 1) chunk = 1;
    if (chunk > 16) chunk = 16;

    const int M = BB * LL;  // 4096
    dim3 blk(256);
    dim3 gT(DM / 32, DM / 32);
    dim3 gP(M / 8);
    dim3 g64(DM / 64, M / 64);

    hipLaunchKernelGGL(transpose1024, gT, blk, 0, stream, Wq, Wt1);
    hipLaunchKernelGGL(transpose1024, gT, blk, 0, stream, Wk, Wt2);
    hipLaunchKernelGGL(proj_emul, gP, blk, 0, stream, x, Wt1, bq, Qf);
    hipLaunchKernelGGL(proj_emul, gP, blk, 0, stream, x, Wt2, bk, Kf);
    hipLaunchKernelGGL((gemm_f32<0>), g64, blk, 0, stream, x, Wv, bv, Vf, M, DM, DM);

    for (int bh0 = 0; bh0 < BB * NH; bh0 += chunk) {
        int nb = BB * NH - bh0;
        if (nb > chunk) nb = chunk;
        dim3 gA(LL / 16, nb);
        dim3 gS(LL / 8, nb);
        hipLaunchKernelGGL(score_np,  gA, blk, 0, stream, Qf, Kf, scw, bh0);
        hipLaunchKernelGGL(select_np, gS, blk, 0, stream, scw, Vf, ctx, U, bh0);
    }

    hipLaunchKernelGGL((gemm_f32<1>), g64, blk, 0, stream, ctx, Wo, bo, out, M, DM, DM);
}